// Round 1
// baseline (1028.392 us; speedup 1.0000x reference)
//
#include <hip/hip_runtime.h>
#include <math.h>

// Problem constants
#define B_SZ 8
#define L_SZ 2048
#define D_SZ 512
#define M_SZ (B_SZ * L_SZ)  // 16384

__device__ __forceinline__ float gelu_exact(float x) {
    return 0.5f * x * (1.0f + erff(x * 0.7071067811865475f));
}
__device__ __forceinline__ float sigmoid_f(float x) {
    return 1.0f / (1.0f + expf(-x));
}

// ---------------------------------------------------------------------------
// Causal depthwise conv1d: k=4, left-pad 3.  xc[b,l,d] = bias[d] + sum_k x[b,l-3+k,d]*w[d,k]
// ---------------------------------------------------------------------------
__global__ __launch_bounds__(256) void conv_kernel(
    const float* __restrict__ x, const float* __restrict__ w,
    const float* __restrict__ bias, float* __restrict__ xc) {
    int idx = blockIdx.x * 256 + threadIdx.x;
    if (idx >= M_SZ * D_SZ) return;
    int d = idx & (D_SZ - 1);
    int bl = idx / D_SZ;          // b*L + l
    int l = bl & (L_SZ - 1);
    float acc = bias[d];
#pragma unroll
    for (int k = 0; k < 4; ++k) {
        int ll = l - 3 + k;
        if (ll >= 0) acc += x[(size_t)(bl - 3 + k) * D_SZ + d] * w[d * 4 + k];
    }
    xc[idx] = acc;
}

// ---------------------------------------------------------------------------
// fp32 tiled GEMM: C(M,N) = A(M,K) @ B, 64x64 tile, 4x4 per thread.
// BTRANS=0: B is (K,N) row-major.  BTRANS=1: B is (N,K) row-major (i.e. A @ B^T).
// OP: 0 = gelu(acc)
//     1 = sigmoid(aux + acc)
//     2 = acc
//     3 = gelu(P[t]*acc + Q[t]*R[row])          (t = row % L)
//     4 = aux + P[t]*acc + Q[t]*R[row]
// ---------------------------------------------------------------------------
template <int OP, int BTRANS>
__global__ __launch_bounds__(256) void gemm64(
    const float* __restrict__ A, const float* __restrict__ Bm, float* __restrict__ C,
    int M, int N, int K,
    const float* __restrict__ aux,
    const float* __restrict__ Pv, const float* __restrict__ Qv,
    const float* __restrict__ Rv) {
    __shared__ float As[16][68];
    __shared__ float Bs[16][68];
    int tid = threadIdx.x;
    int tx = tid & 15, ty = tid >> 4;
    int row0 = blockIdx.y * 64;
    int col0 = blockIdx.x * 64;
    float acc[4][4] = {};

    int lm = tid >> 2;          // 0..63
    int lk = (tid & 3) << 2;    // 0,4,8,12

    for (int k0 = 0; k0 < K; k0 += 16) {
        {   // A tile: As[k][m]
            const float4 a4 = *(const float4*)&A[(size_t)(row0 + lm) * K + k0 + lk];
            As[lk + 0][lm] = a4.x; As[lk + 1][lm] = a4.y;
            As[lk + 2][lm] = a4.z; As[lk + 3][lm] = a4.w;
        }
        if (BTRANS) {
            const float4 b4 = *(const float4*)&Bm[(size_t)(col0 + lm) * K + k0 + lk];
            Bs[lk + 0][lm] = b4.x; Bs[lk + 1][lm] = b4.y;
            Bs[lk + 2][lm] = b4.z; Bs[lk + 3][lm] = b4.w;
        } else {
            int bn = (tid & 15) << 2;
            int bk = tid >> 4;
            const float4 b4 = *(const float4*)&Bm[(size_t)(k0 + bk) * N + col0 + bn];
            *(float4*)&Bs[bk][bn] = b4;
        }
        __syncthreads();
#pragma unroll
        for (int k = 0; k < 16; ++k) {
            float4 a4 = *(const float4*)&As[k][ty << 2];
            float4 b4 = *(const float4*)&Bs[k][tx << 2];
            float ar[4] = {a4.x, a4.y, a4.z, a4.w};
            float br[4] = {b4.x, b4.y, b4.z, b4.w};
#pragma unroll
            for (int i = 0; i < 4; ++i)
#pragma unroll
                for (int j = 0; j < 4; ++j) acc[i][j] += ar[i] * br[j];
        }
        __syncthreads();
    }

#pragma unroll
    for (int i = 0; i < 4; ++i) {
        int r = row0 + (ty << 2) + i;
        int t = r & (L_SZ - 1);
        float p = 0.f, qs = 0.f, rs = 0.f;
        if (OP >= 3) { p = Pv[t]; qs = Qv[t]; rs = Rv[r]; }
        float out[4];
#pragma unroll
        for (int j = 0; j < 4; ++j) {
            int c = col0 + (tx << 2) + j;
            float v = acc[i][j];
            if (OP == 0) v = gelu_exact(v);
            else if (OP == 1) v = sigmoid_f(aux[(size_t)r * N + c] + v);
            else if (OP == 3) v = gelu_exact(p * v + qs * rs);
            else if (OP == 4) v = aux[(size_t)r * N + c] + p * v + qs * rs;
            out[j] = v;
        }
        *(float4*)&C[(size_t)r * N + col0 + (tx << 2)] =
            make_float4(out[0], out[1], out[2], out[3]);
    }
}

// ---------------------------------------------------------------------------
// Block reduce helper (256 threads = 4 waves of 64)
// ---------------------------------------------------------------------------
__device__ __forceinline__ float block_reduce_sum256(float v, float* sred) {
#pragma unroll
    for (int o = 32; o > 0; o >>= 1) v += __shfl_xor(v, o, 64);
    int lane = threadIdx.x & 63, w = threadIdx.x >> 6;
    if (lane == 0) sred[w] = v;
    __syncthreads();
    float r = sred[0] + sred[1] + sred[2] + sred[3];
    __syncthreads();
    return r;
}

// mean over (b, d) for each l:   out[l] = mean_{b,d} buf[b,l,d]
__global__ __launch_bounds__(256) void mean_l_kernel(const float* __restrict__ buf,
                                                     float* __restrict__ out) {
    __shared__ float sred[4];
    int l = blockIdx.x;
    int tid = threadIdx.x;
    float s = 0.f;
    for (int b = 0; b < B_SZ; ++b) {
        const float* row = buf + ((size_t)b * L_SZ + l) * D_SZ;
        for (int d = tid; d < D_SZ; d += 256) s += row[d];
    }
    float tot = block_reduce_sum256(s, sred);
    if (tid == 0) out[l] = tot / (float)(B_SZ * D_SZ);
}

// L2-normalize each row (in place) and write S[n] = rowsum of normalized row
__global__ __launch_bounds__(256) void l2norm_kernel(float* __restrict__ q,
                                                     float* __restrict__ S) {
    __shared__ float sred[4];
    int n = blockIdx.x;
    int tid = threadIdx.x;
    float* row = q + (size_t)n * D_SZ;
    float v0 = row[tid], v1 = row[tid + 256];
    float ss = block_reduce_sum256(v0 * v0 + v1 * v1, sred);
    float nrm = sqrtf(ss);
    float scale = 1.0f / fmaxf(nrm, 1e-12f);
    v0 *= scale; v1 *= scale;
    float rs = block_reduce_sum256(v0 + v1, sred);
    row[tid] = v0; row[tid + 256] = v1;
    if (tid == 0) S[n] = rs;
}

// R[n] = rowsum of G
__global__ __launch_bounds__(256) void rowsum_kernel(const float* __restrict__ G,
                                                     float* __restrict__ R) {
    __shared__ float sred[4];
    int n = blockIdx.x;
    int tid = threadIdx.x;
    const float* row = G + (size_t)n * D_SZ;
    float s = row[tid] + row[tid + 256];
    float tot = block_reduce_sum256(s, sred);
    if (tid == 0) R[n] = tot;
}

// Sequential scalar scan: P[t], Q[t] from alpha_mean (a) and eta_mean (e)
__global__ __launch_bounds__(256) void scan_kernel(const float* __restrict__ a,
                                                   const float* __restrict__ e,
                                                   float* __restrict__ P,
                                                   float* __restrict__ Q) {
    __shared__ float sa[L_SZ], se[L_SZ];
    for (int i = threadIdx.x; i < L_SZ; i += 256) { sa[i] = a[i]; se[i] = e[i]; }
    __syncthreads();
    if (threadIdx.x == 0) {
        float p = 1.f, q = 0.f;
        for (int t = 0; t < L_SZ; ++t) {
            P[t] = p; Q[t] = q;
            float at = sa[t], et = se[t];
            q = q * at - 0.01f * et;
            p = p * at;
        }
    }
}

// ---------------------------------------------------------------------------
extern "C" void kernel_launch(void* const* d_in, const int* in_sizes, int n_in,
                              void* d_out, int out_size, void* d_ws, size_t ws_size,
                              hipStream_t stream) {
    const float* x       = (const float*)d_in[0];
    const float* conv_w  = (const float*)d_in[1];
    const float* conv_b  = (const float*)d_in[2];
    const float* q_w     = (const float*)d_in[3];
    const float* mem_w1  = (const float*)d_in[4];
    const float* mem_w2  = (const float*)d_in[5];
    const float* eta_w1  = (const float*)d_in[6];
    const float* eta_w2  = (const float*)d_in[7];
    const float* alpha_w1= (const float*)d_in[8];
    const float* alpha_w2= (const float*)d_in[9];
    float* out = (float*)d_out;

    const size_t big = (size_t)M_SZ * D_SZ;  // 8388608 floats
    float* xc        = (float*)d_ws;
    float* buf1      = xc + big;
    float* buf2      = buf1 + big;
    float* eta_mean  = buf2 + big;
    float* alpha_mean= eta_mean + L_SZ;
    float* Pv        = alpha_mean + L_SZ;
    float* Qv        = Pv + L_SZ;
    float* Sv        = Qv + L_SZ;      // 16384
    float* Rv        = Sv + M_SZ;      // 16384

    const int M = M_SZ, N = D_SZ, K = D_SZ;
    dim3 ggrid(N / 64, M / 64);
    dim3 gblk(256);

    // 1. depthwise causal conv
    conv_kernel<<<(M_SZ * D_SZ) / 256, 256, 0, stream>>>(x, conv_w, conv_b, xc);

    // 2-4. eta branch: sigmoid(xc + gelu(xc@eta_w1)@eta_w2), mean over (b,d)
    gemm64<0, 0><<<ggrid, gblk, 0, stream>>>(xc, eta_w1, buf1, M, N, K,
                                             nullptr, nullptr, nullptr, nullptr);
    gemm64<1, 0><<<ggrid, gblk, 0, stream>>>(buf1, eta_w2, buf2, M, N, K,
                                             xc, nullptr, nullptr, nullptr);
    mean_l_kernel<<<L_SZ, 256, 0, stream>>>(buf2, eta_mean);

    // 5-7. alpha branch
    gemm64<0, 0><<<ggrid, gblk, 0, stream>>>(xc, alpha_w1, buf1, M, N, K,
                                             nullptr, nullptr, nullptr, nullptr);
    gemm64<1, 0><<<ggrid, gblk, 0, stream>>>(buf1, alpha_w2, buf2, M, N, K,
                                             xc, nullptr, nullptr, nullptr);
    mean_l_kernel<<<L_SZ, 256, 0, stream>>>(buf2, alpha_mean);

    // 8. scalar scan for P_t, Q_t
    scan_kernel<<<1, 256, 0, stream>>>(alpha_mean, eta_mean, Pv, Qv);

    // 9-10. q = l2norm(xc @ q_w^T), S = rowsum(q)
    gemm64<2, 1><<<ggrid, gblk, 0, stream>>>(xc, q_w, buf1, M, N, K,
                                             nullptr, nullptr, nullptr, nullptr);
    l2norm_kernel<<<M_SZ, 256, 0, stream>>>(buf1, Sv);

    // 11-12. G = gelu(P_t*(q@mem_w1) + Q_t*S), R = rowsum(G)
    gemm64<3, 0><<<ggrid, gblk, 0, stream>>>(buf1, mem_w1, buf2, M, N, K,
                                             nullptr, Pv, Qv, Sv);
    rowsum_kernel<<<M_SZ, 256, 0, stream>>>(buf2, Rv);

    // 13. out = q + P_t*(G@mem_w2) + Q_t*R
    gemm64<4, 0><<<ggrid, gblk, 0, stream>>>(buf2, mem_w2, out, M, N, K,
                                             buf1, Pv, Qv, Rv);
}

// Round 2
// 312.065 us; speedup vs baseline: 3.2954x; 3.2954x over previous
//
#include <hip/hip_runtime.h>
#include <math.h>

constexpr int Bn = 8, Ln = 2048, Dn = 512;
constexpr int Mn = Bn * Ln;  // 16384

typedef __bf16 bf16x8 __attribute__((ext_vector_type(8)));
typedef float f32x4 __attribute__((ext_vector_type(4)));

__device__ __forceinline__ float gelu_exact(float x) {
    return 0.5f * x * (1.0f + erff(x * 0.7071067811865475f));
}
__device__ __forceinline__ float sigmoid_f(float x) {
    return 1.0f / (1.0f + expf(-x));
}

// ---------------------------------------------------------------------------
// Causal depthwise conv1d (k=4, left-pad 3) -> xc fp32 (for sigmoid aux) + bf16
// ---------------------------------------------------------------------------
__global__ __launch_bounds__(256) void conv_kernel(
    const float* __restrict__ x, const float* __restrict__ w,
    const float* __restrict__ bias, float* __restrict__ xc,
    __bf16* __restrict__ xcb) {
    int idx = blockIdx.x * 256 + threadIdx.x;
    int d = idx & (Dn - 1);
    int bl = idx / Dn;
    int l = bl & (Ln - 1);
    float acc = bias[d];
#pragma unroll
    for (int k = 0; k < 4; ++k) {
        int ll = l - 3 + k;
        if (ll >= 0) acc += x[(size_t)(bl - 3 + k) * Dn + d] * w[d * 4 + k];
    }
    xc[idx] = acc;
    xcb[idx] = (__bf16)acc;
}

// ---------------------------------------------------------------------------
// Weight convert: z=0..5 transpose (K,N)->(N,K) + bf16; z=6 straight convert
// ---------------------------------------------------------------------------
__global__ __launch_bounds__(256) void wconv_kernel(
    const float* __restrict__ ew1, const float* __restrict__ aw1,
    const float* __restrict__ ew2, const float* __restrict__ aw2,
    const float* __restrict__ mw1, const float* __restrict__ mw2,
    const float* __restrict__ qw,
    __bf16* __restrict__ Wht, __bf16* __restrict__ W2t,
    __bf16* __restrict__ m1t, __bf16* __restrict__ m2t,
    __bf16* __restrict__ qwt) {
    __shared__ float tile[64][65];
    int z = blockIdx.z;
    const float* src;
    __bf16* dst;
    int trans = 1;
    switch (z) {
        case 0: src = ew1; dst = Wht; break;
        case 1: src = aw1; dst = Wht + 512 * 512; break;
        case 2: src = ew2; dst = W2t; break;
        case 3: src = aw2; dst = W2t + 512 * 512; break;
        case 4: src = mw1; dst = m1t; break;
        case 5: src = mw2; dst = m2t; break;
        default: src = qw; dst = qwt; trans = 0; break;
    }
    int r0 = blockIdx.y * 64, c0 = blockIdx.x * 64;
    if (!trans) {
        for (int i = threadIdx.x; i < 4096; i += 256) {
            int r = i >> 6, c = i & 63;
            dst[(size_t)(r0 + r) * 512 + c0 + c] = (__bf16)src[(size_t)(r0 + r) * 512 + c0 + c];
        }
        return;
    }
    for (int i = threadIdx.x; i < 4096; i += 256) {
        int r = i >> 6, c = i & 63;
        tile[r][c] = src[(size_t)(r0 + r) * 512 + c0 + c];
    }
    __syncthreads();
    for (int i = threadIdx.x; i < 4096; i += 256) {
        int r = i >> 6, c = i & 63;
        dst[(size_t)(c0 + r) * 512 + r0 + c] = (__bf16)tile[c][r];
    }
}

// ---------------------------------------------------------------------------
// bf16 MFMA GEMM (m97 structure): C = A(M x 512) @ Bt^T, Bt is (N x 512) row-major.
// 128x128 tile, 4 waves each 64x64, 16x16x32 MFMA, global_load_lds 16B staging.
// OP: 0=gelu->bf16  1=sigmoid(aux+acc)->bf16  2=acc->f32
//     3=gelu(P*acc+Q*R)->bf16  4=aux+P*acc+Q*R->f32
// ---------------------------------------------------------------------------
template <int OP>
__global__ __launch_bounds__(256, 2) void gemm_mfma(
    const __bf16* __restrict__ A, int lda, int Az,
    const __bf16* __restrict__ Bt, int Bz,
    void* __restrict__ Cptr, int ldc, int Cz,
    const float* __restrict__ aux,
    const float* __restrict__ Pv, const float* __restrict__ Qv,
    const float* __restrict__ Rv) {
    __shared__ __align__(16) __bf16 Asl[128 * 32];
    __shared__ __align__(16) __bf16 Bsl[128 * 32];
    const int tid = threadIdx.x;
    const int lane = tid & 63, wv = tid >> 6;
    const int wm = wv & 1, wn = wv >> 1;
    const int fr = lane & 15, fq = lane >> 4;
    const int z = blockIdx.z;
    A += (size_t)z * Az;
    Bt += (size_t)z * Bz;
    const __bf16* Ab = A + (size_t)blockIdx.y * 128 * lda;
    const __bf16* Bb = Bt + (size_t)blockIdx.x * 128 * 512;

    f32x4 acc[4][4] = {};

    for (int k0 = 0; k0 < 512; k0 += 32) {
#pragma unroll
        for (int i = 0; i < 2; ++i) {
            int c = tid + i * 256;
            int r = c >> 2, co = (c & 3) * 8;
            __builtin_amdgcn_global_load_lds(
                (const __attribute__((address_space(1))) void*)(Ab + (size_t)r * lda + k0 + co),
                (__attribute__((address_space(3))) void*)(Asl + c * 8), 16, 0, 0);
            __builtin_amdgcn_global_load_lds(
                (const __attribute__((address_space(1))) void*)(Bb + (size_t)r * 512 + k0 + co),
                (__attribute__((address_space(3))) void*)(Bsl + c * 8), 16, 0, 0);
        }
        __syncthreads();
        bf16x8 af[4], bfr[4];
#pragma unroll
        for (int mi = 0; mi < 4; ++mi)
            af[mi] = *(const bf16x8*)&Asl[(wm * 64 + mi * 16 + fr) * 32 + fq * 8];
#pragma unroll
        for (int ni = 0; ni < 4; ++ni)
            bfr[ni] = *(const bf16x8*)&Bsl[(wn * 64 + ni * 16 + fr) * 32 + fq * 8];
#pragma unroll
        for (int mi = 0; mi < 4; ++mi)
#pragma unroll
            for (int ni = 0; ni < 4; ++ni)
                acc[mi][ni] = __builtin_amdgcn_mfma_f32_16x16x32_bf16(af[mi], bfr[ni], acc[mi][ni], 0, 0, 0);
        __syncthreads();
    }

    const int row_base = blockIdx.y * 128 + wm * 64;
    const int col_base = blockIdx.x * 128 + wn * 64;  // local col within z-slice
    const int coff = z * Cz;
#pragma unroll
    for (int mi = 0; mi < 4; ++mi) {
#pragma unroll
        for (int r = 0; r < 4; ++r) {
            int row = row_base + mi * 16 + fq * 4 + r;
            float p = 0.f, qs = 0.f, rs = 0.f;
            if (OP >= 3) { int t = row & (Ln - 1); p = Pv[t]; qs = Qv[t]; rs = Rv[row]; }
#pragma unroll
            for (int ni = 0; ni < 4; ++ni) {
                int col = col_base + ni * 16 + fr;
                float v = acc[mi][ni][r];
                if (OP == 0) v = gelu_exact(v);
                else if (OP == 1) v = sigmoid_f(aux[(size_t)row * 512 + col] + v);
                else if (OP == 3) v = gelu_exact(p * v + qs * rs);
                else if (OP == 4) v = aux[(size_t)row * 512 + col] + p * v + qs * rs;
                if (OP == 0 || OP == 1 || OP == 3)
                    ((__bf16*)Cptr)[(size_t)row * ldc + coff + col] = (__bf16)v;
                else
                    ((float*)Cptr)[(size_t)row * ldc + coff + col] = v;
            }
        }
    }
}

// ---------------------------------------------------------------------------
__device__ __forceinline__ float block_reduce_sum256(float v, float* sred) {
#pragma unroll
    for (int o = 32; o > 0; o >>= 1) v += __shfl_xor(v, o, 64);
    int lane = threadIdx.x & 63, w = threadIdx.x >> 6;
    if (lane == 0) sred[w] = v;
    __syncthreads();
    float r = sred[0] + sred[1] + sred[2] + sred[3];
    __syncthreads();
    return r;
}

// eta_mean / alpha_mean: Sg is (M x 1024) bf16; cols 0..511 eta, 512..1023 alpha
__global__ __launch_bounds__(256) void mean2_kernel(const __bf16* __restrict__ Sg,
                                                    float* __restrict__ em,
                                                    float* __restrict__ am) {
    __shared__ float sred[4];
    int l = blockIdx.x, tid = threadIdx.x;
    float s = 0.f;
    for (int b = 0; b < Bn; ++b) {
        const __bf16* row = Sg + ((size_t)b * Ln + l) * 1024 + tid * 4;
        s += (float)row[0] + (float)row[1] + (float)row[2] + (float)row[3];
    }
#pragma unroll
    for (int o = 32; o > 0; o >>= 1) s += __shfl_xor(s, o, 64);
    int lane = tid & 63, wv = tid >> 6;
    if (!lane) sred[wv] = s;
    __syncthreads();
    if (!tid) {
        em[l] = (sred[0] + sred[1]) / 4096.f;
        am[l] = (sred[2] + sred[3]) / 4096.f;
    }
}

// Parallel scan over L=2048 affine transforms: q -> a*q - 0.01*e, p -> a*p.
// Exclusive prefix: P[t] = prod_{s<t} a_s, Q via composition.
__global__ __launch_bounds__(256) void scan_kernel(const float* __restrict__ a,
                                                   const float* __restrict__ e,
                                                   float* __restrict__ P,
                                                   float* __restrict__ Q) {
    int tid = threadIdx.x;
    int base = tid * 8;
    float la[8], le[8], Aloc[8], Bloc[8];
#pragma unroll
    for (int j = 0; j < 8; ++j) { la[j] = a[base + j]; le[j] = e[base + j]; }
    float Ac = 1.f, Bc = 0.f;
#pragma unroll
    for (int j = 0; j < 8; ++j) {
        Aloc[j] = Ac; Bloc[j] = Bc;
        Bc = Bc * la[j] - 0.01f * le[j];
        Ac *= la[j];
    }
    // wave inclusive scan of composites (combine(left,right): A=Ar*Al, B=Ar*Bl+Br)
    float Aw = Ac, Bw = Bc;
#pragma unroll
    for (int off = 1; off < 64; off <<= 1) {
        float Ap = __shfl_up(Aw, off, 64);
        float Bp = __shfl_up(Bw, off, 64);
        if ((tid & 63) >= off) { Bw = Aw * Bp + Bw; Aw = Aw * Ap; }
    }
    __shared__ float wA[4], wB[4];
    if ((tid & 63) == 63) { wA[tid >> 6] = Aw; wB[tid >> 6] = Bw; }
    __syncthreads();
    float Apre = 1.f, Bpre = 0.f;
    for (int w = 0; w < (tid >> 6); ++w) { Bpre = wA[w] * Bpre + wB[w]; Apre = wA[w] * Apre; }
    // lane-exclusive within wave
    float Ax = __shfl_up(Aw, 1, 64), Bx = __shfl_up(Bw, 1, 64);
    if ((tid & 63) == 0) { Ax = 1.f; Bx = 0.f; }
    float At = Ax * Apre, Bt2 = Ax * Bpre + Bx;
#pragma unroll
    for (int j = 0; j < 8; ++j) {
        P[base + j] = Aloc[j] * At;
        Q[base + j] = Aloc[j] * Bt2 + Bloc[j];
    }
}

// L2-normalize rows of q (in place), emit bf16 copy + rowsum S
__global__ __launch_bounds__(256) void l2norm_kernel(float* __restrict__ q,
                                                     __bf16* __restrict__ qb,
                                                     float* __restrict__ S) {
    __shared__ float sred[4];
    int n = blockIdx.x, tid = threadIdx.x;
    float* row = q + (size_t)n * Dn;
    float v0 = row[tid], v1 = row[tid + 256];
    float ss = block_reduce_sum256(v0 * v0 + v1 * v1, sred);
    float sc = 1.f / fmaxf(sqrtf(ss), 1e-12f);
    v0 *= sc; v1 *= sc;
    float rs = block_reduce_sum256(v0 + v1, sred);
    row[tid] = v0; row[tid + 256] = v1;
    qb[(size_t)n * Dn + tid] = (__bf16)v0;
    qb[(size_t)n * Dn + tid + 256] = (__bf16)v1;
    if (!tid) S[n] = rs;
}

// R[n] = rowsum of G (bf16)
__global__ __launch_bounds__(256) void rowsum_kernel(const __bf16* __restrict__ G,
                                                     float* __restrict__ R) {
    __shared__ float sred[4];
    int n = blockIdx.x, tid = threadIdx.x;
    const __bf16* row = G + (size_t)n * Dn;
    float s = (float)row[tid] + (float)row[tid + 256];
    float tot = block_reduce_sum256(s, sred);
    if (!tid) R[n] = tot;
}

// ---------------------------------------------------------------------------
extern "C" void kernel_launch(void* const* d_in, const int* in_sizes, int n_in,
                              void* d_out, int out_size, void* d_ws, size_t ws_size,
                              hipStream_t stream) {
    const float* x        = (const float*)d_in[0];
    const float* conv_w   = (const float*)d_in[1];
    const float* conv_b   = (const float*)d_in[2];
    const float* q_w      = (const float*)d_in[3];
    const float* mem_w1   = (const float*)d_in[4];
    const float* mem_w2   = (const float*)d_in[5];
    const float* eta_w1   = (const float*)d_in[6];
    const float* eta_w2   = (const float*)d_in[7];
    const float* alpha_w1 = (const float*)d_in[8];
    const float* alpha_w2 = (const float*)d_in[9];
    float* out = (float*)d_out;

    char* w = (char*)d_ws;
    float* xc = (float*)w;            w += (size_t)Mn * Dn * 4;   // 33.55 MB (later: Qpre/q_fp32)
    __bf16* xcb = (__bf16*)w;         w += (size_t)Mn * Dn * 2;   // 16.78 MB (later: G)
    __bf16* Wht = (__bf16*)w;         w += (size_t)1024 * 512 * 2;
    __bf16* W2t = (__bf16*)w;         w += (size_t)2 * 512 * 512 * 2;
    __bf16* qwt = (__bf16*)w;         w += (size_t)512 * 512 * 2;
    __bf16* m1t = (__bf16*)w;         w += (size_t)512 * 512 * 2;
    __bf16* m2t = (__bf16*)w;         w += (size_t)512 * 512 * 2;
    float* eta_mean = (float*)w;      w += Ln * 4;
    float* alpha_mean = (float*)w;    w += Ln * 4;
    float* Pv = (float*)w;            w += Ln * 4;
    float* Qv = (float*)w;            w += Ln * 4;
    float* Sv = (float*)w;            w += (size_t)Mn * 4;
    float* Rv = (float*)w;            w += (size_t)Mn * 4;
    __bf16* H = (__bf16*)w;           w += (size_t)Mn * 1024 * 2; // 33.55 MB (later: q_bf16)

    __bf16* Sg = (__bf16*)d_out;  // M x 1024 bf16 scratch, exactly fits d_out
    float* Qpre = xc;             // aliases xc after its last use (GEMM_s aux)
    __bf16* qb = H;               // aliases H after GEMM_s
    __bf16* G = xcb;              // aliases xcb after GEMM_q

    // 1. conv -> xc fp32 + bf16
    conv_kernel<<<Mn * Dn / 256, 256, 0, stream>>>(x, conv_w, conv_b, xc, xcb);
    // 2. weight convert/transpose
    wconv_kernel<<<dim3(8, 8, 7), 256, 0, stream>>>(eta_w1, alpha_w1, eta_w2, alpha_w2,
                                                    mem_w1, mem_w2, q_w,
                                                    Wht, W2t, m1t, m2t, qwt);
    // 3. H = gelu(xc @ [eta_w1 | alpha_w1])   (M x 1024, bf16)
    gemm_mfma<0><<<dim3(8, 128, 1), 256, 0, stream>>>(xcb, 512, 0, Wht, 0,
                                                      H, 1024, 0, nullptr, nullptr, nullptr, nullptr);
    // 4. Sg = sigmoid(xc + H_half @ w2)  for eta (z=0), alpha (z=1)
    gemm_mfma<1><<<dim3(4, 128, 2), 256, 0, stream>>>(H, 1024, 512, W2t, 512 * 512,
                                                      Sg, 1024, 512, xc, nullptr, nullptr, nullptr);
    // 5. per-l means
    mean2_kernel<<<Ln, 256, 0, stream>>>(Sg, eta_mean, alpha_mean);
    // 6. P/Q prefix scan
    scan_kernel<<<1, 256, 0, stream>>>(alpha_mean, eta_mean, Pv, Qv);
    // 7. Qpre = xc @ q_w^T  (fp32)
    gemm_mfma<2><<<dim3(4, 128, 1), 256, 0, stream>>>(xcb, 512, 0, qwt, 0,
                                                      Qpre, 512, 0, nullptr, nullptr, nullptr, nullptr);
    // 8. l2norm in place + bf16 copy + rowsums S
    l2norm_kernel<<<Mn, 256, 0, stream>>>(Qpre, qb, Sv);
    // 9. G = gelu(P*(q @ mem_w1) + Q*S)  (bf16)
    gemm_mfma<3><<<dim3(4, 128, 1), 256, 0, stream>>>(qb, 512, 0, m1t, 0,
                                                      G, 512, 0, nullptr, Pv, Qv, Sv);
    // 10. R = rowsum(G)
    rowsum_kernel<<<Mn, 256, 0, stream>>>(G, Rv);
    // 11. out = q + P*(G @ mem_w2) + Q*R
    gemm_mfma<4><<<dim3(4, 128, 1), 256, 0, stream>>>(G, 512, 0, m2t, 0,
                                                      out, 512, 0, Qpre, Pv, Qv, Rv);
}

// Round 3
// 283.188 us; speedup vs baseline: 3.6315x; 1.1020x over previous
//
#include <hip/hip_runtime.h>
#include <math.h>

constexpr int Bn = 8, Ln = 2048, Dn = 512;
constexpr int Mn = Bn * Ln;  // 16384

typedef __bf16 bf16x8 __attribute__((ext_vector_type(8)));
typedef __bf16 bf16x4v __attribute__((ext_vector_type(4)));
typedef __bf16 bf16x2v __attribute__((ext_vector_type(2)));
typedef float f32x4 __attribute__((ext_vector_type(4)));

__device__ __forceinline__ float gelu_exact(float x) {
    return 0.5f * x * (1.0f + erff(x * 0.7071067811865475f));
}
__device__ __forceinline__ float sigmoid_f(float x) {
    return 1.0f / (1.0f + expf(-x));
}

// ---------------------------------------------------------------------------
// Causal depthwise conv1d (k=4, left-pad 3) -> bf16 only, float4 vectorized.
// Each thread: 4 consecutive channels at one (b,l).
// ---------------------------------------------------------------------------
__global__ __launch_bounds__(256) void conv_kernel(
    const float* __restrict__ x, const float* __restrict__ w,
    const float* __restrict__ bias, __bf16* __restrict__ xcb) {
    int idx = blockIdx.x * 256 + threadIdx.x;   // Mn*Dn/4 threads
    int g = idx & 127;                          // channel group
    int bl = idx >> 7;
    int l = bl & (Ln - 1);
    int d = g * 4;
    float a[4];
    float4 b4 = *(const float4*)&bias[d];
    a[0] = b4.x; a[1] = b4.y; a[2] = b4.z; a[3] = b4.w;
    float wv[16];  // wv[j*4+k] = weight for channel d+j, tap k
    *(float4*)&wv[0]  = *(const float4*)&w[d * 4];
    *(float4*)&wv[4]  = *(const float4*)&w[d * 4 + 4];
    *(float4*)&wv[8]  = *(const float4*)&w[d * 4 + 8];
    *(float4*)&wv[12] = *(const float4*)&w[d * 4 + 12];
#pragma unroll
    for (int k = 0; k < 4; ++k) {
        int ll = l - 3 + k;
        if (ll >= 0) {
            float4 xv = *(const float4*)&x[(size_t)(bl - 3 + k) * Dn + d];
            a[0] += xv.x * wv[0 * 4 + k];
            a[1] += xv.y * wv[1 * 4 + k];
            a[2] += xv.z * wv[2 * 4 + k];
            a[3] += xv.w * wv[3 * 4 + k];
        }
    }
    bf16x4v o = { (__bf16)a[0], (__bf16)a[1], (__bf16)a[2], (__bf16)a[3] };
    *(bf16x4v*)&xcb[(size_t)bl * Dn + d] = o;
}

// ---------------------------------------------------------------------------
// Weight convert: z=0..5 transpose (K,N)->(N,K) + bf16; z=6 straight convert
// ---------------------------------------------------------------------------
__global__ __launch_bounds__(256) void wconv_kernel(
    const float* __restrict__ ew1, const float* __restrict__ aw1,
    const float* __restrict__ ew2, const float* __restrict__ aw2,
    const float* __restrict__ mw1, const float* __restrict__ mw2,
    const float* __restrict__ qw,
    __bf16* __restrict__ Wht, __bf16* __restrict__ W2t,
    __bf16* __restrict__ m1t, __bf16* __restrict__ m2t,
    __bf16* __restrict__ qwt) {
    __shared__ float tile[64][65];
    int z = blockIdx.z;
    const float* src;
    __bf16* dst;
    int trans = 1;
    switch (z) {
        case 0: src = ew1; dst = Wht; break;
        case 1: src = aw1; dst = Wht + 512 * 512; break;
        case 2: src = ew2; dst = W2t; break;
        case 3: src = aw2; dst = W2t + 512 * 512; break;
        case 4: src = mw1; dst = m1t; break;
        case 5: src = mw2; dst = m2t; break;
        default: src = qw; dst = qwt; trans = 0; break;
    }
    int r0 = blockIdx.y * 64, c0 = blockIdx.x * 64;
    if (!trans) {
        for (int i = threadIdx.x; i < 4096; i += 256) {
            int r = i >> 6, c = i & 63;
            dst[(size_t)(r0 + r) * 512 + c0 + c] = (__bf16)src[(size_t)(r0 + r) * 512 + c0 + c];
        }
        return;
    }
    for (int i = threadIdx.x; i < 4096; i += 256) {
        int r = i >> 6, c = i & 63;
        tile[r][c] = src[(size_t)(r0 + r) * 512 + c0 + c];
    }
    __syncthreads();
    for (int i = threadIdx.x; i < 4096; i += 256) {
        int r = i >> 6, c = i & 63;
        dst[(size_t)(c0 + r) * 512 + r0 + c] = (__bf16)tile[c][r];
    }
}

// ---------------------------------------------------------------------------
// bf16 MFMA GEMM: C = A(128-row tile x 512) @ Bt^T, Bt (N x 512) row-major.
// OP: 0 = gelu(acc)            -> bf16 store
//     1 = sigmoid(auxb+acc)    -> NO store; atomicAdd per-l mean into red[z*Ln + l]
//     2 = acc                  -> bf16 store
//     3 = gelu(P*acc+Q*R)      -> bf16 store + atomicAdd rowsum into red[row]
//     4 = auxb + P*acc + Q*R   -> f32 store
// ---------------------------------------------------------------------------
template <int OP>
__global__ __launch_bounds__(256, 2) void gemm_mfma(
    const __bf16* __restrict__ A, int lda, int Az,
    const __bf16* __restrict__ Bt, int Bz,
    void* __restrict__ Cptr, int ldc,
    const __bf16* __restrict__ auxb,
    const float* __restrict__ Pv, const float* __restrict__ Qv,
    const float* __restrict__ Rv,
    float* __restrict__ red) {
    __shared__ __align__(16) __bf16 Asl[128 * 32];
    __shared__ __align__(16) __bf16 Bsl[128 * 32];
    const int tid = threadIdx.x;
    const int lane = tid & 63, wv = tid >> 6;
    const int wm = wv & 1, wn = wv >> 1;
    const int fr = lane & 15, fq = lane >> 4;
    const int z = blockIdx.z;
    A += (size_t)z * Az;
    Bt += (size_t)z * Bz;
    const __bf16* Ab = A + (size_t)blockIdx.y * 128 * lda;
    const __bf16* Bb = Bt + (size_t)blockIdx.x * 128 * 512;
    float* redp = (OP == 1) ? red + (size_t)z * Ln : red;

    f32x4 acc[4][4] = {};

    for (int k0 = 0; k0 < 512; k0 += 32) {
#pragma unroll
        for (int i = 0; i < 2; ++i) {
            int c = tid + i * 256;
            int r = c >> 2, co = (c & 3) * 8;
            __builtin_amdgcn_global_load_lds(
                (const __attribute__((address_space(1))) void*)(Ab + (size_t)r * lda + k0 + co),
                (__attribute__((address_space(3))) void*)(Asl + c * 8), 16, 0, 0);
            __builtin_amdgcn_global_load_lds(
                (const __attribute__((address_space(1))) void*)(Bb + (size_t)r * 512 + k0 + co),
                (__attribute__((address_space(3))) void*)(Bsl + c * 8), 16, 0, 0);
        }
        __syncthreads();
        bf16x8 af[4], bfr[4];
#pragma unroll
        for (int mi = 0; mi < 4; ++mi)
            af[mi] = *(const bf16x8*)&Asl[(wm * 64 + mi * 16 + fr) * 32 + fq * 8];
#pragma unroll
        for (int ni = 0; ni < 4; ++ni)
            bfr[ni] = *(const bf16x8*)&Bsl[(wn * 64 + ni * 16 + fr) * 32 + fq * 8];
#pragma unroll
        for (int mi = 0; mi < 4; ++mi)
#pragma unroll
            for (int ni = 0; ni < 4; ++ni)
                acc[mi][ni] = __builtin_amdgcn_mfma_f32_16x16x32_bf16(af[mi], bfr[ni], acc[mi][ni], 0, 0, 0);
        __syncthreads();
    }

    const int row_base = blockIdx.y * 128 + wm * 64;
    const int col_base = blockIdx.x * 128 + wn * 64;
#pragma unroll
    for (int mi = 0; mi < 4; ++mi) {
#pragma unroll
        for (int r = 0; r < 4; ++r) {
            int row = row_base + mi * 16 + fq * 4 + r;
            float p = 0.f, qs = 0.f, rs = 0.f;
            if (OP >= 3) { int t = row & (Ln - 1); p = Pv[t]; qs = Qv[t]; rs = Rv[row]; }
            float s = 0.f;
#pragma unroll
            for (int ni = 0; ni < 4; ++ni) {
                int col = col_base + ni * 16 + fr;
                float v = acc[mi][ni][r];
                if (OP == 0) v = gelu_exact(v);
                else if (OP == 1) v = sigmoid_f((float)auxb[(size_t)row * 512 + col] + v);
                else if (OP == 3) v = gelu_exact(p * v + qs * rs);
                else if (OP == 4) v = (float)auxb[(size_t)row * 512 + col] + p * v + qs * rs;
                if (OP == 0 || OP == 2 || OP == 3)
                    ((__bf16*)Cptr)[(size_t)row * ldc + col] = (__bf16)v;
                else if (OP == 4)
                    ((float*)Cptr)[(size_t)row * ldc + col] = v;
                s += v;
            }
            if (OP == 1 || OP == 3) {
                // reduce s across the 16 fr lanes (same row)
                s += __shfl_xor(s, 1, 64);
                s += __shfl_xor(s, 2, 64);
                s += __shfl_xor(s, 4, 64);
                s += __shfl_xor(s, 8, 64);
                if (fr == 0) {
                    if (OP == 1) atomicAdd(&redp[row & (Ln - 1)], s * (1.0f / 4096.0f));
                    else atomicAdd(&redp[row], s);
                }
            }
        }
    }
}

// ---------------------------------------------------------------------------
__device__ __forceinline__ float block_reduce_sum256(float v, float* sred) {
#pragma unroll
    for (int o = 32; o > 0; o >>= 1) v += __shfl_xor(v, o, 64);
    int lane = threadIdx.x & 63, w = threadIdx.x >> 6;
    if (lane == 0) sred[w] = v;
    __syncthreads();
    float r = sred[0] + sred[1] + sred[2] + sred[3];
    __syncthreads();
    return r;
}

// Parallel scan over L=2048 affine maps q -> a*q - 0.01*e.  Exclusive prefixes.
__global__ __launch_bounds__(256) void scan_kernel(const float* __restrict__ a,
                                                   const float* __restrict__ e,
                                                   float* __restrict__ P,
                                                   float* __restrict__ Q) {
    int tid = threadIdx.x;
    int base = tid * 8;
    float la[8], le[8], Aloc[8], Bloc[8];
#pragma unroll
    for (int j = 0; j < 8; ++j) { la[j] = a[base + j]; le[j] = e[base + j]; }
    float Ac = 1.f, Bc = 0.f;
#pragma unroll
    for (int j = 0; j < 8; ++j) {
        Aloc[j] = Ac; Bloc[j] = Bc;
        Bc = Bc * la[j] - 0.01f * le[j];
        Ac *= la[j];
    }
    float Aw = Ac, Bw = Bc;
#pragma unroll
    for (int off = 1; off < 64; off <<= 1) {
        float Ap = __shfl_up(Aw, off, 64);
        float Bp = __shfl_up(Bw, off, 64);
        if ((tid & 63) >= off) { Bw = Aw * Bp + Bw; Aw = Aw * Ap; }
    }
    __shared__ float wA[4], wB[4];
    if ((tid & 63) == 63) { wA[tid >> 6] = Aw; wB[tid >> 6] = Bw; }
    __syncthreads();
    float Apre = 1.f, Bpre = 0.f;
    for (int w = 0; w < (tid >> 6); ++w) { Bpre = wA[w] * Bpre + wB[w]; Apre = wA[w] * Apre; }
    float Ax = __shfl_up(Aw, 1, 64), Bx = __shfl_up(Bw, 1, 64);
    if ((tid & 63) == 0) { Ax = 1.f; Bx = 0.f; }
    float At = Ax * Apre, Bt2 = Ax * Bpre + Bx;
#pragma unroll
    for (int j = 0; j < 8; ++j) {
        P[base + j] = Aloc[j] * At;
        Q[base + j] = Aloc[j] * Bt2 + Bloc[j];
    }
}

// L2-normalize bf16 rows in place (vectorized bf16x2) + rowsum S
__global__ __launch_bounds__(256) void l2norm_kernel(__bf16* __restrict__ q,
                                                     float* __restrict__ S) {
    __shared__ float sred[4];
    int n = blockIdx.x, tid = threadIdx.x;
    __bf16* row = q + (size_t)n * Dn;
    bf16x2v v = ((bf16x2v*)row)[tid];
    float f0 = (float)v.x, f1 = (float)v.y;
    float ss = block_reduce_sum256(f0 * f0 + f1 * f1, sred);
    float sc = 1.f / fmaxf(sqrtf(ss), 1e-12f);
    f0 *= sc; f1 *= sc;
    float rs = block_reduce_sum256(f0 + f1, sred);
    bf16x2v o = { (__bf16)f0, (__bf16)f1 };
    ((bf16x2v*)row)[tid] = o;
    if (!tid) S[n] = rs;
}

// ---------------------------------------------------------------------------
extern "C" void kernel_launch(void* const* d_in, const int* in_sizes, int n_in,
                              void* d_out, int out_size, void* d_ws, size_t ws_size,
                              hipStream_t stream) {
    const float* x        = (const float*)d_in[0];
    const float* conv_w   = (const float*)d_in[1];
    const float* conv_b   = (const float*)d_in[2];
    const float* q_w      = (const float*)d_in[3];
    const float* mem_w1   = (const float*)d_in[4];
    const float* mem_w2   = (const float*)d_in[5];
    const float* eta_w1   = (const float*)d_in[6];
    const float* eta_w2   = (const float*)d_in[7];
    const float* alpha_w1 = (const float*)d_in[8];
    const float* alpha_w2 = (const float*)d_in[9];
    float* out = (float*)d_out;

    char* w = (char*)d_ws;
    __bf16* xcb = (__bf16*)w;     w += (size_t)Mn * Dn * 2;       // 16.8 MB
    __bf16* H   = (__bf16*)w;     w += (size_t)Mn * 1024 * 2;     // 33.6 MB
    __bf16* qb  = (__bf16*)w;     w += (size_t)Mn * Dn * 2;       // 16.8 MB
    __bf16* G   = (__bf16*)w;     w += (size_t)Mn * Dn * 2;       // 16.8 MB
    __bf16* Wht = (__bf16*)w;     w += (size_t)1024 * 512 * 2;
    __bf16* W2t = (__bf16*)w;     w += (size_t)2 * 512 * 512 * 2;
    __bf16* qwt = (__bf16*)w;     w += (size_t)512 * 512 * 2;
    __bf16* m1t = (__bf16*)w;     w += (size_t)512 * 512 * 2;
    __bf16* m2t = (__bf16*)w;     w += (size_t)512 * 512 * 2;
    float* Rv      = (float*)w;   w += (size_t)Mn * 4;            // zero-init zone start
    float* MeanAcc = (float*)w;   w += (size_t)2 * Ln * 4;        // [0..Ln)=eta, [Ln..2Ln)=alpha
    float* Pv = (float*)w;        w += Ln * 4;
    float* Qv = (float*)w;        w += Ln * 4;
    float* Sv = (float*)w;        w += (size_t)Mn * 4;

    // zero atomic-reduction targets (Rv + MeanAcc contiguous)
    hipMemsetAsync(Rv, 0, (size_t)(Mn + 2 * Ln) * 4, stream);

    // 1. conv -> bf16
    conv_kernel<<<Mn * Dn / 4 / 256, 256, 0, stream>>>(x, conv_w, conv_b, xcb);
    // 2. weight convert/transpose
    wconv_kernel<<<dim3(8, 8, 7), 256, 0, stream>>>(eta_w1, alpha_w1, eta_w2, alpha_w2,
                                                    mem_w1, mem_w2, q_w,
                                                    Wht, W2t, m1t, m2t, qwt);
    // 3. H = gelu(xc @ [eta_w1 | alpha_w1])  (M x 1024 bf16)
    gemm_mfma<0><<<dim3(8, 128, 1), 256, 0, stream>>>(xcb, 512, 0, Wht, 0,
                                                      H, 1024, nullptr, nullptr, nullptr, nullptr, nullptr);
    // 4. per-l means of sigmoid(xc + H_half @ w2), fused reduction (no store)
    gemm_mfma<1><<<dim3(4, 128, 2), 256, 0, stream>>>(H, 1024, 512, W2t, 512 * 512,
                                                      nullptr, 0, xcb, nullptr, nullptr, nullptr, MeanAcc);
    // 5. P/Q prefix scan  (a = alpha, e = eta)
    scan_kernel<<<1, 256, 0, stream>>>(MeanAcc + Ln, MeanAcc, Pv, Qv);
    // 6. qb = xc @ q_w^T  (bf16)
    gemm_mfma<2><<<dim3(4, 128, 1), 256, 0, stream>>>(xcb, 512, 0, qwt, 0,
                                                      qb, 512, nullptr, nullptr, nullptr, nullptr, nullptr);
    // 7. l2norm in place + rowsum S
    l2norm_kernel<<<Mn, 256, 0, stream>>>(qb, Sv);
    // 8. G = gelu(P*(q @ mem_w1) + Q*S)  + fused rowsum R
    gemm_mfma<3><<<dim3(4, 128, 1), 256, 0, stream>>>(qb, 512, 0, m1t, 0,
                                                      G, 512, nullptr, Pv, Qv, Sv, Rv);
    // 9. out = q + P*(G @ mem_w2) + Q*R
    gemm_mfma<4><<<dim3(4, 128, 1), 256, 0, stream>>>(G, 512, 0, m2t, 0,
                                                      out, 512, qb, Pv, Qv, Rv, nullptr);
}

// Round 4
// 262.951 us; speedup vs baseline: 3.9110x; 1.0770x over previous
//
#include <hip/hip_runtime.h>
#include <math.h>

constexpr int Bn = 8, Ln = 2048, Dn = 512;
constexpr int Mn = Bn * Ln;  // 16384
constexpr int CONV_BLOCKS = Mn * Dn / 4 / 256;  // 8192

typedef __bf16 bf16x8 __attribute__((ext_vector_type(8)));
typedef __bf16 bf16x4v __attribute__((ext_vector_type(4)));
typedef float f32x4 __attribute__((ext_vector_type(4)));

__device__ __forceinline__ float gelu_exact(float x) {
    return 0.5f * x * (1.0f + erff(x * 0.7071067811865475f));
}
__device__ __forceinline__ float sigmoid_fast(float x) {
    // v_exp_f32 + v_rcp_f32: ~1ulp each, plenty within tolerance
    return __builtin_amdgcn_rcpf(1.0f + __expf(-x));
}

// ---------------------------------------------------------------------------
// Fused: causal depthwise conv1d (blocks < CONV_BLOCKS) + weight prep (rest).
// Wall = [eta_w1^T ; alpha_w1^T ; q_w] (1536 x 512) bf16.
// ---------------------------------------------------------------------------
__global__ __launch_bounds__(256) void prep_kernel(
    const float* __restrict__ x, const float* __restrict__ w,
    const float* __restrict__ bias, __bf16* __restrict__ xcb,
    const float* __restrict__ ew1, const float* __restrict__ aw1,
    const float* __restrict__ ew2, const float* __restrict__ aw2,
    const float* __restrict__ mw1, const float* __restrict__ mw2,
    const float* __restrict__ qw,
    __bf16* __restrict__ Wall, __bf16* __restrict__ W2t,
    __bf16* __restrict__ m1t, __bf16* __restrict__ m2t) {
    __shared__ float tile[64][65];
    if (blockIdx.x < CONV_BLOCKS) {
        int idx = blockIdx.x * 256 + threadIdx.x;
        int g = idx & 127;
        int bl = idx >> 7;
        int l = bl & (Ln - 1);
        int d = g * 4;
        float a[4];
        float4 b4 = *(const float4*)&bias[d];
        a[0] = b4.x; a[1] = b4.y; a[2] = b4.z; a[3] = b4.w;
        float wv[16];
        *(float4*)&wv[0]  = *(const float4*)&w[d * 4];
        *(float4*)&wv[4]  = *(const float4*)&w[d * 4 + 4];
        *(float4*)&wv[8]  = *(const float4*)&w[d * 4 + 8];
        *(float4*)&wv[12] = *(const float4*)&w[d * 4 + 12];
#pragma unroll
        for (int k = 0; k < 4; ++k) {
            int ll = l - 3 + k;
            if (ll >= 0) {
                float4 xv = *(const float4*)&x[(size_t)(bl - 3 + k) * Dn + d];
                a[0] += xv.x * wv[0 * 4 + k];
                a[1] += xv.y * wv[1 * 4 + k];
                a[2] += xv.z * wv[2 * 4 + k];
                a[3] += xv.w * wv[3 * 4 + k];
            }
        }
        bf16x4v o = { (__bf16)a[0], (__bf16)a[1], (__bf16)a[2], (__bf16)a[3] };
        *(bf16x4v*)&xcb[(size_t)bl * Dn + d] = o;
        return;
    }
    // weight prep: 448 blocks = 7 z-slices x 64 tiles
    int bid = blockIdx.x - CONV_BLOCKS;
    int z = bid >> 6;
    int t = bid & 63;
    int r0 = (t >> 3) * 64, c0 = (t & 7) * 64;
    const float* src;
    __bf16* dst;
    int trans = 1;
    switch (z) {
        case 0: src = ew1; dst = Wall; break;
        case 1: src = aw1; dst = Wall + 512 * 512; break;
        case 2: src = ew2; dst = W2t; break;
        case 3: src = aw2; dst = W2t + 512 * 512; break;
        case 4: src = mw1; dst = m1t; break;
        case 5: src = mw2; dst = m2t; break;
        default: src = qw; dst = Wall + 1024 * 512; trans = 0; break;
    }
    if (!trans) {
        for (int i = threadIdx.x; i < 4096; i += 256) {
            int r = i >> 6, c = i & 63;
            dst[(size_t)(r0 + r) * 512 + c0 + c] = (__bf16)src[(size_t)(r0 + r) * 512 + c0 + c];
        }
        return;
    }
    for (int i = threadIdx.x; i < 4096; i += 256) {
        int r = i >> 6, c = i & 63;
        tile[r][c] = src[(size_t)(r0 + r) * 512 + c0 + c];
    }
    __syncthreads();
    for (int i = threadIdx.x; i < 4096; i += 256) {
        int r = i >> 6, c = i & 63;
        dst[(size_t)(c0 + r) * 512 + r0 + c] = (__bf16)tile[c][r];
    }
}

// ---------------------------------------------------------------------------
// bf16 MFMA GEMM, BM x 128 tile (BM = 128 or 64), K = 512, Bt is (N x 512).
// OP 0: fused H|q.  x-blocks [0,8): H = gelu(acc) -> bf16 (ldc 1024)
//                   x-blocks [8,12): qraw -> bf16 (ldc 512) + atomic RS/SS per row
// OP 1: sigmoid-mean: s = sigmoid(aux + acc); atomic mean into red[z*Ln + l]; no store
// OP 3: G = gelu(inv*(P*acc + Q*RS)) -> bf16 + atomic rowsum red[row]
// OP 4: out = aux*inv + P*acc + Q*Rv  -> fp32
// ---------------------------------------------------------------------------
template <int OP, int BM>
__global__ __launch_bounds__(256, 2) void gemm_mfma(
    const __bf16* __restrict__ A, int lda, int Az,
    const __bf16* __restrict__ Bt, int Bz,
    void* __restrict__ C0, void* __restrict__ C1,
    const __bf16* __restrict__ auxb,
    const float* __restrict__ Pv, const float* __restrict__ Qv,
    const float* __restrict__ SSv, const float* __restrict__ RSv,
    float* __restrict__ red0, float* __restrict__ red1, float* __restrict__ red2) {
    constexpr int MI = BM / 32;        // acc rows per wave / 16
    constexpr int AISS = BM / 64;      // A-staging 16B issues per thread
    __shared__ __align__(16) __bf16 Asl[BM * 32];
    __shared__ __align__(16) __bf16 Bsl[128 * 32];
    const int tid = threadIdx.x;
    const int lane = tid & 63, wv = tid >> 6;
    const int wm = wv & 1, wn = wv >> 1;
    const int fr = lane & 15, fq = lane >> 4;
    const int z = blockIdx.z;
    A += (size_t)z * Az;
    Bt += (size_t)z * Bz;
    const __bf16* Ab = A + (size_t)blockIdx.y * BM * lda;
    const __bf16* Bb = Bt + (size_t)blockIdx.x * 128 * 512;
    float* redp = (OP == 1) ? red0 + (size_t)z * Ln : red0;

    f32x4 acc[MI][4] = {};

    for (int k0 = 0; k0 < 512; k0 += 32) {
#pragma unroll
        for (int i = 0; i < AISS; ++i) {
            int c = tid + i * 256;
            int r = c >> 2, co = (c & 3) * 8;
            __builtin_amdgcn_global_load_lds(
                (const __attribute__((address_space(1))) void*)(Ab + (size_t)r * lda + k0 + co),
                (__attribute__((address_space(3))) void*)(Asl + c * 8), 16, 0, 0);
        }
#pragma unroll
        for (int i = 0; i < 2; ++i) {
            int c = tid + i * 256;
            int r = c >> 2, co = (c & 3) * 8;
            __builtin_amdgcn_global_load_lds(
                (const __attribute__((address_space(1))) void*)(Bb + (size_t)r * 512 + k0 + co),
                (__attribute__((address_space(3))) void*)(Bsl + c * 8), 16, 0, 0);
        }
        __syncthreads();
        bf16x8 af[MI], bfr[4];
#pragma unroll
        for (int mi = 0; mi < MI; ++mi)
            af[mi] = *(const bf16x8*)&Asl[(wm * (BM / 2) + mi * 16 + fr) * 32 + fq * 8];
#pragma unroll
        for (int ni = 0; ni < 4; ++ni)
            bfr[ni] = *(const bf16x8*)&Bsl[(wn * 64 + ni * 16 + fr) * 32 + fq * 8];
#pragma unroll
        for (int mi = 0; mi < MI; ++mi)
#pragma unroll
            for (int ni = 0; ni < 4; ++ni)
                acc[mi][ni] = __builtin_amdgcn_mfma_f32_16x16x32_bf16(af[mi], bfr[ni], acc[mi][ni], 0, 0, 0);
        __syncthreads();
    }

    const int row_base = blockIdx.y * BM + wm * (BM / 2);
    const int col_base = blockIdx.x * 128 + wn * 64;
    const bool qpath = (OP == 0) && (blockIdx.x >= 8);
#pragma unroll
    for (int mi = 0; mi < MI; ++mi) {
#pragma unroll
        for (int r = 0; r < 4; ++r) {
            int row = row_base + mi * 16 + fq * 4 + r;
            float p = 0.f, qs = 0.f, rs = 0.f, inv = 1.f;
            if (OP >= 3) {
                int t = row & (Ln - 1);
                p = Pv[t]; qs = Qv[t];
                rs = RSv[row];
                inv = 1.0f / fmaxf(sqrtf(SSv[row]), 1e-12f);
            }
            float s1 = 0.f, s2 = 0.f;
#pragma unroll
            for (int ni = 0; ni < 4; ++ni) {
                int col = col_base + ni * 16 + fr;
                float v = acc[mi][ni][r];
                if (OP == 0) {
                    if (!qpath) {
                        v = gelu_exact(v);
                        ((__bf16*)C0)[(size_t)row * 1024 + col] = (__bf16)v;
                    } else {
                        ((__bf16*)C1)[(size_t)row * 512 + col - 1024] = (__bf16)v;
                        s1 += v; s2 += v * v;
                    }
                } else if (OP == 1) {
                    v = sigmoid_fast((float)auxb[(size_t)row * 512 + col] + v);
                    s1 += v;
                } else if (OP == 3) {
                    v = gelu_exact(inv * (p * v + qs * rs));
                    ((__bf16*)C0)[(size_t)row * 512 + col] = (__bf16)v;
                    s1 += v;
                } else if (OP == 4) {
                    float qn = (float)auxb[(size_t)row * 512 + col] * inv;
                    ((float*)C0)[(size_t)row * 512 + col] = qn + p * v + qs * rs;
                }
            }
            if (OP == 1 || OP == 3 || (OP == 0 && qpath)) {
                s1 += __shfl_xor(s1, 1, 64);
                s1 += __shfl_xor(s1, 2, 64);
                s1 += __shfl_xor(s1, 4, 64);
                s1 += __shfl_xor(s1, 8, 64);
                if (OP == 0) {
                    s2 += __shfl_xor(s2, 1, 64);
                    s2 += __shfl_xor(s2, 2, 64);
                    s2 += __shfl_xor(s2, 4, 64);
                    s2 += __shfl_xor(s2, 8, 64);
                }
                if (fr == 0) {
                    if (OP == 1) atomicAdd(&redp[row & (Ln - 1)], s1 * (1.0f / 4096.0f));
                    else if (OP == 3) atomicAdd(&red0[row], s1);
                    else { atomicAdd(&red1[row], s2); atomicAdd(&red2[row], s1); }
                }
            }
        }
    }
}

// ---------------------------------------------------------------------------
// Parallel scan over L=2048 affine maps q -> a*q - 0.01*e.  Exclusive prefixes.
// ---------------------------------------------------------------------------
__global__ __launch_bounds__(256) void scan_kernel(const float* __restrict__ a,
                                                   const float* __restrict__ e,
                                                   float* __restrict__ P,
                                                   float* __restrict__ Q) {
    int tid = threadIdx.x;
    int base = tid * 8;
    float la[8], le[8], Aloc[8], Bloc[8];
#pragma unroll
    for (int j = 0; j < 8; ++j) { la[j] = a[base + j]; le[j] = e[base + j]; }
    float Ac = 1.f, Bc = 0.f;
#pragma unroll
    for (int j = 0; j < 8; ++j) {
        Aloc[j] = Ac; Bloc[j] = Bc;
        Bc = Bc * la[j] - 0.01f * le[j];
        Ac *= la[j];
    }
    float Aw = Ac, Bw = Bc;
#pragma unroll
    for (int off = 1; off < 64; off <<= 1) {
        float Ap = __shfl_up(Aw, off, 64);
        float Bp = __shfl_up(Bw, off, 64);
        if ((tid & 63) >= off) { Bw = Aw * Bp + Bw; Aw = Aw * Ap; }
    }
    __shared__ float wA[4], wB[4];
    if ((tid & 63) == 63) { wA[tid >> 6] = Aw; wB[tid >> 6] = Bw; }
    __syncthreads();
    float Apre = 1.f, Bpre = 0.f;
    for (int w = 0; w < (tid >> 6); ++w) { Bpre = wA[w] * Bpre + wB[w]; Apre = wA[w] * Apre; }
    float Ax = __shfl_up(Aw, 1, 64), Bx = __shfl_up(Bw, 1, 64);
    if ((tid & 63) == 0) { Ax = 1.f; Bx = 0.f; }
    float At = Ax * Apre, Bt2 = Ax * Bpre + Bx;
#pragma unroll
    for (int j = 0; j < 8; ++j) {
        P[base + j] = Aloc[j] * At;
        Q[base + j] = Aloc[j] * Bt2 + Bloc[j];
    }
}

// ---------------------------------------------------------------------------
extern "C" void kernel_launch(void* const* d_in, const int* in_sizes, int n_in,
                              void* d_out, int out_size, void* d_ws, size_t ws_size,
                              hipStream_t stream) {
    const float* x        = (const float*)d_in[0];
    const float* conv_w   = (const float*)d_in[1];
    const float* conv_b   = (const float*)d_in[2];
    const float* q_w      = (const float*)d_in[3];
    const float* mem_w1   = (const float*)d_in[4];
    const float* mem_w2   = (const float*)d_in[5];
    const float* eta_w1   = (const float*)d_in[6];
    const float* eta_w2   = (const float*)d_in[7];
    const float* alpha_w1 = (const float*)d_in[8];
    const float* alpha_w2 = (const float*)d_in[9];
    float* out = (float*)d_out;

    char* w = (char*)d_ws;
    __bf16* xcb  = (__bf16*)w;    w += (size_t)Mn * Dn * 2;       // 16.8 MB
    __bf16* H    = (__bf16*)w;    w += (size_t)Mn * 1024 * 2;     // 33.6 MB
    __bf16* qb   = (__bf16*)w;    w += (size_t)Mn * Dn * 2;       // 16.8 MB
    __bf16* G    = (__bf16*)w;    w += (size_t)Mn * Dn * 2;       // 16.8 MB
    __bf16* Wall = (__bf16*)w;    w += (size_t)1536 * 512 * 2;    // [ew1^T; aw1^T; qw]
    __bf16* W2t  = (__bf16*)w;    w += (size_t)2 * 512 * 512 * 2;
    __bf16* m1t  = (__bf16*)w;    w += (size_t)512 * 512 * 2;
    __bf16* m2t  = (__bf16*)w;    w += (size_t)512 * 512 * 2;
    float* Rv      = (float*)w;   w += (size_t)Mn * 4;            // zero zone start
    float* MeanAcc = (float*)w;   w += (size_t)2 * Ln * 4;
    float* SS      = (float*)w;   w += (size_t)Mn * 4;
    float* RS      = (float*)w;   w += (size_t)Mn * 4;            // zero zone end
    float* Pv = (float*)w;        w += Ln * 4;
    float* Qv = (float*)w;        w += Ln * 4;

    hipMemsetAsync(Rv, 0, (size_t)(Mn + 2 * Ln + Mn + Mn) * 4, stream);

    // 1. conv + weight prep (fused)
    prep_kernel<<<CONV_BLOCKS + 448, 256, 0, stream>>>(
        x, conv_w, conv_b, xcb, eta_w1, alpha_w1, eta_w2, alpha_w2,
        mem_w1, mem_w2, q_w, Wall, W2t, m1t, m2t);
    // 2. fused: H = gelu(xcb @ [ew1|aw1]) ; qraw = xcb @ qw^T (+SS/RS atomics)
    gemm_mfma<0, 128><<<dim3(12, 128), 256, 0, stream>>>(
        xcb, 512, 0, Wall, 0, H, qb, nullptr,
        nullptr, nullptr, nullptr, nullptr, nullptr, SS, RS);
    // 3. per-l means of sigmoid(xc + H_half @ w2)  (z=0 eta, z=1 alpha)
    gemm_mfma<1, 128><<<dim3(4, 128, 2), 256, 0, stream>>>(
        H, 1024, 512, W2t, 512 * 512, nullptr, nullptr, xcb,
        nullptr, nullptr, nullptr, nullptr, MeanAcc, nullptr, nullptr);
    // 4. P/Q prefix scan (a = alpha, e = eta)
    scan_kernel<<<1, 256, 0, stream>>>(MeanAcc + Ln, MeanAcc, Pv, Qv);
    // 5. G = gelu(inv*(P*(qraw@m1) + Q*RS)) + fused rowsum Rv
    gemm_mfma<3, 64><<<dim3(4, 256), 256, 0, stream>>>(
        qb, 512, 0, m1t, 0, G, nullptr, nullptr,
        Pv, Qv, SS, RS, Rv, nullptr, nullptr);
    // 6. out = qraw*inv + P*(G@m2) + Q*Rv
    gemm_mfma<4, 64><<<dim3(4, 256), 256, 0, stream>>>(
        G, 512, 0, m2t, 0, out, nullptr, qb,
        Pv, Qv, SS, Rv, nullptr, nullptr, nullptr);
}

// Round 5
// 245.641 us; speedup vs baseline: 4.1866x; 1.0705x over previous
//
#include <hip/hip_runtime.h>
#include <math.h>

constexpr int Bn = 8, Ln = 2048, Dn = 512;
constexpr int Mn = Bn * Ln;  // 16384
constexpr int CONV_BLOCKS = Mn * Dn / 16 / 256;     // 2048 (4 l x 4 ch per thread)
constexpr int WPREP_BLOCKS = 448;                   // 7 x 64
constexpr int ZERO_FLOATS = 3 * Mn + 2 * Ln;        // Rv + MeanAcc + SS + RS
constexpr int ZERO_BLOCKS = ZERO_FLOATS / (256 * 4);  // 52

typedef __bf16 bf16x8 __attribute__((ext_vector_type(8)));
typedef __bf16 bf16x4v __attribute__((ext_vector_type(4)));
typedef float f32x4 __attribute__((ext_vector_type(4)));

__device__ __forceinline__ float gelu_exact(float x) {
    return 0.5f * x * (1.0f + erff(x * 0.7071067811865475f));
}
__device__ __forceinline__ float sigmoid_fast(float x) {
    return __builtin_amdgcn_rcpf(1.0f + __expf(-x));
}

// ---------------------------------------------------------------------------
// Fused prep: conv (blocks [0,CONV)), weight prep, zero atomic targets.
// Wall = [eta_w1^T ; alpha_w1^T ; q_w] (1536 x 512) bf16.
// ---------------------------------------------------------------------------
__global__ __launch_bounds__(256) void prep_kernel(
    const float* __restrict__ x, const float* __restrict__ w,
    const float* __restrict__ bias, __bf16* __restrict__ xcb,
    const float* __restrict__ ew1, const float* __restrict__ aw1,
    const float* __restrict__ ew2, const float* __restrict__ aw2,
    const float* __restrict__ mw1, const float* __restrict__ mw2,
    const float* __restrict__ qw,
    __bf16* __restrict__ Wall, __bf16* __restrict__ W2t,
    __bf16* __restrict__ m1t, __bf16* __restrict__ m2t,
    float* __restrict__ zero_zone) {
    __shared__ float tile[64][65];
    if (blockIdx.x < CONV_BLOCKS) {
        // thread -> (b, l0..l0+3, d..d+3)
        int idx = blockIdx.x * 256 + threadIdx.x;
        int g = idx & 127;             // channel group
        int r4 = idx >> 7;             // (b*Ln + l0)/4
        int bl0 = r4 * 4;
        int l0 = bl0 & (Ln - 1);
        int d = g * 4;
        float4 b4 = *(const float4*)&bias[d];
        float wv[16];  // wv[c*4+k]
        *(float4*)&wv[0]  = *(const float4*)&w[d * 4];
        *(float4*)&wv[4]  = *(const float4*)&w[d * 4 + 4];
        *(float4*)&wv[8]  = *(const float4*)&w[d * 4 + 8];
        *(float4*)&wv[12] = *(const float4*)&w[d * 4 + 12];
        float4 xv[7];
#pragma unroll
        for (int t = 0; t < 7; ++t) {
            int ll = l0 - 3 + t;
            xv[t] = (ll >= 0 && t < 7) ? *(const float4*)&x[(size_t)(bl0 - 3 + t) * Dn + d]
                                       : make_float4(0.f, 0.f, 0.f, 0.f);
            if (t >= 3) {  // taps l0..l0+3 always valid
                if (l0 - 3 + t < Ln) xv[t] = *(const float4*)&x[(size_t)(bl0 - 3 + t) * Dn + d];
            }
        }
#pragma unroll
        for (int i = 0; i < 4; ++i) {
            float a0 = b4.x, a1 = b4.y, a2 = b4.z, a3 = b4.w;
#pragma unroll
            for (int k = 0; k < 4; ++k) {
                float4 xt = xv[i + k];
                a0 += xt.x * wv[0 * 4 + k];
                a1 += xt.y * wv[1 * 4 + k];
                a2 += xt.z * wv[2 * 4 + k];
                a3 += xt.w * wv[3 * 4 + k];
            }
            bf16x4v o = { (__bf16)a0, (__bf16)a1, (__bf16)a2, (__bf16)a3 };
            *(bf16x4v*)&xcb[(size_t)(bl0 + i) * Dn + d] = o;
        }
        return;
    }
    if (blockIdx.x >= CONV_BLOCKS + WPREP_BLOCKS) {
        // zero the atomic-reduction zone
        int idx = (blockIdx.x - CONV_BLOCKS - WPREP_BLOCKS) * 256 + threadIdx.x;
        ((float4*)zero_zone)[idx] = make_float4(0.f, 0.f, 0.f, 0.f);
        return;
    }
    // weight prep: 448 blocks = 7 z-slices x 64 tiles
    int bid = blockIdx.x - CONV_BLOCKS;
    int z = bid >> 6;
    int t = bid & 63;
    int r0 = (t >> 3) * 64, c0 = (t & 7) * 64;
    const float* src;
    __bf16* dst;
    int trans = 1;
    switch (z) {
        case 0: src = ew1; dst = Wall; break;
        case 1: src = aw1; dst = Wall + 512 * 512; break;
        case 2: src = ew2; dst = W2t; break;
        case 3: src = aw2; dst = W2t + 512 * 512; break;
        case 4: src = mw1; dst = m1t; break;
        case 5: src = mw2; dst = m2t; break;
        default: src = qw; dst = Wall + 1024 * 512; trans = 0; break;
    }
    if (!trans) {
        for (int i = threadIdx.x; i < 4096; i += 256) {
            int r = i >> 6, c = i & 63;
            dst[(size_t)(r0 + r) * 512 + c0 + c] = (__bf16)src[(size_t)(r0 + r) * 512 + c0 + c];
        }
        return;
    }
    for (int i = threadIdx.x; i < 4096; i += 256) {
        int r = i >> 6, c = i & 63;
        tile[r][c] = src[(size_t)(r0 + r) * 512 + c0 + c];
    }
    __syncthreads();
    for (int i = threadIdx.x; i < 4096; i += 256) {
        int r = i >> 6, c = i & 63;
        dst[(size_t)(c0 + r) * 512 + r0 + c] = (__bf16)tile[c][r];
    }
}

// ---------------------------------------------------------------------------
// bf16 MFMA GEMM, BM x 128 tile (BM = 128 or 64), K = 512, Bt is (N x 512).
// OP 0: fused H|q.  x-blocks [0,8): H = gelu(acc) -> bf16 (ldc 1024)
//                   x-blocks [8,12): qraw -> bf16 + atomic SS/RS per row
// OP 1: sigmoid-mean: atomic per-l mean into red0[z*Ln + l]; no store
// OP 3: G = gelu(inv*(P*acc + Q*RS)) -> bf16 + atomic rowsum red0[row]
// OP 4: out = aux*inv + P*acc + Q*Rv  -> fp32
// ---------------------------------------------------------------------------
template <int OP, int BM>
__global__ __launch_bounds__(256, 4) void gemm_mfma(
    const __bf16* __restrict__ A, int lda, int Az,
    const __bf16* __restrict__ Bt, int Bz,
    void* __restrict__ C0, void* __restrict__ C1,
    const __bf16* __restrict__ auxb,
    const float* __restrict__ Pv, const float* __restrict__ Qv,
    const float* __restrict__ SSv, const float* __restrict__ RSv,
    float* __restrict__ red0, float* __restrict__ red1, float* __restrict__ red2) {
    constexpr int MI = BM / 32;
    constexpr int AISS = BM / 64;
    __shared__ __align__(16) __bf16 Asl[BM * 32];
    __shared__ __align__(16) __bf16 Bsl[128 * 32];
    const int tid = threadIdx.x;
    const int lane = tid & 63, wv = tid >> 6;
    const int wm = wv & 1, wn = wv >> 1;
    const int fr = lane & 15, fq = lane >> 4;
    const int z = blockIdx.z;
    A += (size_t)z * Az;
    Bt += (size_t)z * Bz;
    const __bf16* Ab = A + (size_t)blockIdx.y * BM * lda;
    const __bf16* Bb = Bt + (size_t)blockIdx.x * 128 * 512;
    float* redp = (OP == 1) ? red0 + (size_t)z * Ln : red0;

    f32x4 acc[MI][4] = {};

    for (int k0 = 0; k0 < 512; k0 += 32) {
#pragma unroll
        for (int i = 0; i < AISS; ++i) {
            int c = tid + i * 256;
            int r = c >> 2, co = (c & 3) * 8;
            __builtin_amdgcn_global_load_lds(
                (const __attribute__((address_space(1))) void*)(Ab + (size_t)r * lda + k0 + co),
                (__attribute__((address_space(3))) void*)(Asl + c * 8), 16, 0, 0);
        }
#pragma unroll
        for (int i = 0; i < 2; ++i) {
            int c = tid + i * 256;
            int r = c >> 2, co = (c & 3) * 8;
            __builtin_amdgcn_global_load_lds(
                (const __attribute__((address_space(1))) void*)(Bb + (size_t)r * 512 + k0 + co),
                (__attribute__((address_space(3))) void*)(Bsl + c * 8), 16, 0, 0);
        }
        __syncthreads();
        bf16x8 af[MI], bfr[4];
#pragma unroll
        for (int mi = 0; mi < MI; ++mi)
            af[mi] = *(const bf16x8*)&Asl[(wm * (BM / 2) + mi * 16 + fr) * 32 + fq * 8];
#pragma unroll
        for (int ni = 0; ni < 4; ++ni)
            bfr[ni] = *(const bf16x8*)&Bsl[(wn * 64 + ni * 16 + fr) * 32 + fq * 8];
#pragma unroll
        for (int mi = 0; mi < MI; ++mi)
#pragma unroll
            for (int ni = 0; ni < 4; ++ni)
                acc[mi][ni] = __builtin_amdgcn_mfma_f32_16x16x32_bf16(af[mi], bfr[ni], acc[mi][ni], 0, 0, 0);
        __syncthreads();
    }

    const int row_base = blockIdx.y * BM + wm * (BM / 2);
    const int col_base = blockIdx.x * 128 + wn * 64;
    const bool qpath = (OP == 0) && (blockIdx.x >= 8);
#pragma unroll
    for (int mi = 0; mi < MI; ++mi) {
#pragma unroll
        for (int r = 0; r < 4; ++r) {
            int row = row_base + mi * 16 + fq * 4 + r;
            float p = 0.f, qs = 0.f, rs = 0.f, inv = 1.f;
            if (OP >= 3) {
                int t = row & (Ln - 1);
                p = Pv[t]; qs = Qv[t];
                rs = RSv[row];
                inv = 1.0f / fmaxf(sqrtf(SSv[row]), 1e-12f);
            }
            float s1 = 0.f, s2 = 0.f;
#pragma unroll
            for (int ni = 0; ni < 4; ++ni) {
                int col = col_base + ni * 16 + fr;
                float v = acc[mi][ni][r];
                if (OP == 0) {
                    if (!qpath) {
                        v = gelu_exact(v);
                        ((__bf16*)C0)[(size_t)row * 1024 + col] = (__bf16)v;
                    } else {
                        ((__bf16*)C1)[(size_t)row * 512 + col - 1024] = (__bf16)v;
                        s1 += v; s2 += v * v;
                    }
                } else if (OP == 1) {
                    v = sigmoid_fast((float)auxb[(size_t)row * 512 + col] + v);
                    s1 += v;
                } else if (OP == 3) {
                    v = gelu_exact(inv * (p * v + qs * rs));
                    ((__bf16*)C0)[(size_t)row * 512 + col] = (__bf16)v;
                    s1 += v;
                } else if (OP == 4) {
                    float qn = (float)auxb[(size_t)row * 512 + col] * inv;
                    ((float*)C0)[(size_t)row * 512 + col] = qn + p * v + qs * rs;
                }
            }
            if (OP == 1 || OP == 3 || (OP == 0 && qpath)) {
                s1 += __shfl_xor(s1, 1, 64);
                s1 += __shfl_xor(s1, 2, 64);
                s1 += __shfl_xor(s1, 4, 64);
                s1 += __shfl_xor(s1, 8, 64);
                if (OP == 0) {
                    s2 += __shfl_xor(s2, 1, 64);
                    s2 += __shfl_xor(s2, 2, 64);
                    s2 += __shfl_xor(s2, 4, 64);
                    s2 += __shfl_xor(s2, 8, 64);
                }
                if (fr == 0) {
                    if (OP == 1) atomicAdd(&redp[row & (Ln - 1)], s1 * (1.0f / 4096.0f));
                    else if (OP == 3) atomicAdd(&red0[row], s1);
                    else { atomicAdd(&red1[row], s2); atomicAdd(&red2[row], s1); }
                }
            }
        }
    }
}

// ---------------------------------------------------------------------------
// Parallel scan over L=2048 affine maps q -> a*q - 0.01*e.  Exclusive prefixes.
// ---------------------------------------------------------------------------
__global__ __launch_bounds__(256) void scan_kernel(const float* __restrict__ a,
                                                   const float* __restrict__ e,
                                                   float* __restrict__ P,
                                                   float* __restrict__ Q) {
    int tid = threadIdx.x;
    int base = tid * 8;
    float la[8], le[8], Aloc[8], Bloc[8];
#pragma unroll
    for (int j = 0; j < 8; ++j) { la[j] = a[base + j]; le[j] = e[base + j]; }
    float Ac = 1.f, Bc = 0.f;
#pragma unroll
    for (int j = 0; j < 8; ++j) {
        Aloc[j] = Ac; Bloc[j] = Bc;
        Bc = Bc * la[j] - 0.01f * le[j];
        Ac *= la[j];
    }
    float Aw = Ac, Bw = Bc;
#pragma unroll
    for (int off = 1; off < 64; off <<= 1) {
        float Ap = __shfl_up(Aw, off, 64);
        float Bp = __shfl_up(Bw, off, 64);
        if ((tid & 63) >= off) { Bw = Aw * Bp + Bw; Aw = Aw * Ap; }
    }
    __shared__ float wA[4], wB[4];
    if ((tid & 63) == 63) { wA[tid >> 6] = Aw; wB[tid >> 6] = Bw; }
    __syncthreads();
    float Apre = 1.f, Bpre = 0.f;
    for (int w = 0; w < (tid >> 6); ++w) { Bpre = wA[w] * Bpre + wB[w]; Apre = wA[w] * Apre; }
    float Ax = __shfl_up(Aw, 1, 64), Bx = __shfl_up(Bw, 1, 64);
    if ((tid & 63) == 0) { Ax = 1.f; Bx = 0.f; }
    float At = Ax * Apre, Bt2 = Ax * Bpre + Bx;
#pragma unroll
    for (int j = 0; j < 8; ++j) {
        P[base + j] = Aloc[j] * At;
        Q[base + j] = Aloc[j] * Bt2 + Bloc[j];
    }
}

// ---------------------------------------------------------------------------
extern "C" void kernel_launch(void* const* d_in, const int* in_sizes, int n_in,
                              void* d_out, int out_size, void* d_ws, size_t ws_size,
                              hipStream_t stream) {
    const float* x        = (const float*)d_in[0];
    const float* conv_w   = (const float*)d_in[1];
    const float* conv_b   = (const float*)d_in[2];
    const float* q_w      = (const float*)d_in[3];
    const float* mem_w1   = (const float*)d_in[4];
    const float* mem_w2   = (const float*)d_in[5];
    const float* eta_w1   = (const float*)d_in[6];
    const float* eta_w2   = (const float*)d_in[7];
    const float* alpha_w1 = (const float*)d_in[8];
    const float* alpha_w2 = (const float*)d_in[9];
    float* out = (float*)d_out;

    char* w = (char*)d_ws;
    __bf16* xcb  = (__bf16*)w;    w += (size_t)Mn * Dn * 2;
    __bf16* H    = (__bf16*)w;    w += (size_t)Mn * 1024 * 2;
    __bf16* qb   = (__bf16*)w;    w += (size_t)Mn * Dn * 2;
    __bf16* G    = (__bf16*)w;    w += (size_t)Mn * Dn * 2;
    __bf16* Wall = (__bf16*)w;    w += (size_t)1536 * 512 * 2;
    __bf16* W2t  = (__bf16*)w;    w += (size_t)2 * 512 * 512 * 2;
    __bf16* m1t  = (__bf16*)w;    w += (size_t)512 * 512 * 2;
    __bf16* m2t  = (__bf16*)w;    w += (size_t)512 * 512 * 2;
    float* Rv      = (float*)w;   w += (size_t)Mn * 4;            // zero zone start
    float* MeanAcc = (float*)w;   w += (size_t)2 * Ln * 4;
    float* SS      = (float*)w;   w += (size_t)Mn * 4;
    float* RS      = (float*)w;   w += (size_t)Mn * 4;            // zero zone end
    float* Pv = (float*)w;        w += Ln * 4;
    float* Qv = (float*)w;        w += Ln * 4;

    // 1. conv + weight prep + zero (fused)
    prep_kernel<<<CONV_BLOCKS + WPREP_BLOCKS + ZERO_BLOCKS, 256, 0, stream>>>(
        x, conv_w, conv_b, xcb, eta_w1, alpha_w1, eta_w2, alpha_w2,
        mem_w1, mem_w2, q_w, Wall, W2t, m1t, m2t, Rv);
    // 2. fused: H = gelu(xcb @ [ew1|aw1]) ; qraw = xcb @ qw^T (+SS/RS atomics)
    gemm_mfma<0, 128><<<dim3(12, 128), 256, 0, stream>>>(
        xcb, 512, 0, Wall, 0, H, qb, nullptr,
        nullptr, nullptr, nullptr, nullptr, nullptr, SS, RS);
    // 3. per-l means of sigmoid(xc + H_half @ w2)  (z=0 eta, z=1 alpha)
    gemm_mfma<1, 128><<<dim3(4, 128, 2), 256, 0, stream>>>(
        H, 1024, 512, W2t, 512 * 512, nullptr, nullptr, xcb,
        nullptr, nullptr, nullptr, nullptr, MeanAcc, nullptr, nullptr);
    // 4. P/Q prefix scan (a = alpha, e = eta)
    scan_kernel<<<1, 256, 0, stream>>>(MeanAcc + Ln, MeanAcc, Pv, Qv);
    // 5. G = gelu(inv*(P*(qraw@m1) + Q*RS)) + fused rowsum Rv
    gemm_mfma<3, 64><<<dim3(4, 256), 256, 0, stream>>>(
        qb, 512, 0, m1t, 0, G, nullptr, nullptr,
        Pv, Qv, SS, RS, Rv, nullptr, nullptr);
    // 6. out = qraw*inv + P*(G@m2) + Q*Rv
    gemm_mfma<4, 64><<<dim3(4, 256), 256, 0, stream>>>(
        G, 512, 0, m2t, 0, out, nullptr, qb,
        Pv, Qv, SS, Rv, nullptr, nullptr, nullptr);
}